// Round 15
// baseline (71.664 us; speedup 1.0000x reference)
//
#include <hip/hip_runtime.h>
#include <hip/hip_bf16.h>
#include <math.h>

// B=32, T=256, E=C=256, MIN_CONTEXT=64, FUTURE_STEPS=12
// S0=192, NROW=6144, K=256. G = P·X^T (6144x6144), bucketed exp-sums.
// t in [181,192) are singleton tail buckets; bucket0 = t<181. N_terms=71616.

#define NROW 6144
#define TAIL0 181
#define NTERMS 71616.0f
#define LOG2E 1.44269504088896340736f
#define SHIFT2 92.33248261689366f   // 64 * log2(e)

typedef __attribute__((ext_vector_type(8))) short short8;
typedef __attribute__((ext_vector_type(4))) float f32x4;

__device__ __forceinline__ ushort f2bf(float f) {
  union { float f; uint32_t u; } v; v.f = f;
  uint32_t u = v.u;
  return (ushort)((u + 0x7FFFu + ((u >> 16) & 1u)) >> 16);
}
// exp(x - 64) = exp2(x*log2e - 64*log2e)
__device__ __forceinline__ float expsh(float x) {
  return exp2f(fmaf(x, LOG2E, -SHIFT2));
}

// async global->LDS, 16B per lane; lds dst must be wave-uniform base
__device__ __forceinline__ void gload16(const ushort* g, ushort* l) {
  __builtin_amdgcn_global_load_lds((const __attribute__((address_space(1))) void*)g,
                                   (__attribute__((address_space(3))) void*)l, 16, 0, 0);
}

// ---- A0: Wt cast + workspace zeroing (tiny: 281 blocks)
__global__ __launch_bounds__(256) void k_castW(const float* __restrict__ W,
                                               ushort* __restrict__ Wt,
                                               float* __restrict__ zbase) {
  int bi = blockIdx.x;
  if (bi < 256) {
    int c = bi, e = threadIdx.x;
    Wt[c * 256 + e] = f2bf(W[e * 256 + c]);
  } else {
    int idx = (bi - 256) * 256 + threadIdx.x;
    if (idx < 6146) zbase[idx] = 0.f;   // sum0[6144] + acc + cnt
  }
}

// ---- A1+A2 fused: X cast (hidden under proj's MFMA stalls) + P = emb_slice @ W.
// Grid dim3(384,2): flat block id fb in [0,768); each block casts 512 X f4-chunks
// then runs the proj body (block = 16-row tile x 128-col half).
__global__ __launch_bounds__(256) void k_projX(const float* __restrict__ emb,
                                               const float* __restrict__ ctx,
                                               const ushort* __restrict__ Wt,
                                               ushort* __restrict__ X,
                                               ushort* __restrict__ P) {
  __shared__ ushort Al[16 * 256];  // 8KB
  int tid = threadIdx.x;
  int rt = blockIdx.x;             // 384 row tiles
  int half = blockIdx.y;           // col half (128 cols)
  int fb = blockIdx.y * 384 + blockIdx.x;   // 0..767

  // ---- X cast: 393216 f4 chunks total, 512 per block, 2 per thread.
  // X[t*32+j][k] = bf16(ctx[j][63+t][k])
#pragma unroll
  for (int q = 0; q < 2; ++q) {
    int idx = fb * 512 + q * 256 + tid;
    int row = idx >> 6, f4 = idx & 63;  // row = t*32+j
    int j = row & 31, t = row >> 5;
    float4 f = *(const float4*)(ctx + ((size_t)(j * 256 + 63 + t)) * 256 + f4 * 4);
    ushort4 o;
    o.x = f2bf(f.x); o.y = f2bf(f.y); o.z = f2bf(f.z); o.w = f2bf(f.w);
    ((ushort4*)(X + (size_t)row * 256))[f4] = o;
  }

  // ---- proj body: stage A rows (cast to bf16) into LDS, swizzled
#pragma unroll
  for (int q = 0; q < 4; ++q) {
    int cc = tid + q * 256;
    int rw = cc >> 6, f4 = cc & 63;
    int u = rt * 16 + rw, b = u / 192, urow = u - b * 192;
    float4 f = *(const float4*)(emb + ((size_t)(b * 256 + 64 + urow)) * 256 + f4 * 4);
    ushort4 o;
    o.x = f2bf(f.x); o.y = f2bf(f.y); o.z = f2bf(f.z); o.w = f2bf(f.w);
    int c8 = f4 >> 1;
    *(ushort4*)&Al[rw * 256 + ((c8 ^ (rw & 7)) * 8) + (f4 & 1) * 4] = o;
  }
  __syncthreads();

  int w = tid >> 6, l = tid & 63;
  int fr = l & 15, kb = l >> 4;
  short8 af[8];
#pragma unroll
  for (int kk = 0; kk < 8; ++kk) {
    int c8 = kk * 4 + kb;
    af[kk] = *(const short8*)&Al[fr * 256 + (c8 ^ (fr & 7)) * 8];
  }
#pragma unroll
  for (int i = 0; i < 2; ++i) {
    int ct = half * 8 + w * 2 + i;
    const short8* bp = (const short8*)(Wt + (size_t)(ct * 16 + fr) * 256);
    f32x4 acc = {0.f, 0.f, 0.f, 0.f};
#pragma unroll
    for (int kk = 0; kk < 8; ++kk)
      acc = __builtin_amdgcn_mfma_f32_16x16x32_bf16(af[kk], bp[kk * 4 + kb], acc, 0, 0, 0);
#pragma unroll
    for (int r = 0; r < 4; ++r)
      P[(size_t)(rt * 16 + kb * 4 + r) * 256 + ct * 16 + fr] = f2bf(acc[r]);
  }
}

// ---- B: G = P·X^T — r12 VERBATIM (best measured: 47.2us @ 64% occ).
// 512 thr / 8 waves (4 wr x 2 wc), wave 32x32 (acc[2][2] = 16 AGPR, total regs
// ~40 <= 64 -> 8 waves/SIMD), block 128x64, BK=64, 4 rounds of
// stage -> barrier -> ds_read+MFMA -> barrier, single-buffered 24KB LDS.
// By-major grid: concurrent blocks share `by` -> disjoint atomic targets (r10).
// LDS rows hold 8 x 16B chunks, slot XOR-swizzled (slot ^ (row&7)) via
// pre-swizzled GLOBAL source addresses -> conflict-free ds_read_b128.
__global__ __launch_bounds__(512, 8) void k_scores(const ushort* __restrict__ P,
                                                   const ushort* __restrict__ X,
                                                   float* __restrict__ sum0,
                                                   float* __restrict__ tail,
                                                   float* __restrict__ pos) {
  __shared__ ushort Albuf[128 * 64];   // 16KB
  __shared__ ushort Blbuf[64 * 64];    // 8KB
  int tid = threadIdx.x;               // 0..511
  int w = tid >> 6, l = tid & 63;
  int wr = w >> 1, wc = w & 1;         // wr 0..3, wc 0..1
  int rowbase = blockIdx.x * 128;
  int colbase = blockIdx.y * 64;

  int fr = l & 15, kb = l >> 4;

  // staging geometry: A chunk ci = q*512+tid (q=0,1), B chunk ci = tid.
  // row = ci>>3, slot = ci&7 ; src k-chunk = slot ^ (row&7)
  int r0 = tid >> 3;                   // 0..63
  int srcc = (tid & 7) ^ (r0 & 7);
  const ushort* gA = P + (size_t)(rowbase + r0) * 256 + srcc * 8;
  const ushort* gB = X + (size_t)(colbase + r0) * 256 + srcc * 8;

  f32x4 acc[2][2];
#pragma unroll
  for (int m = 0; m < 2; ++m)
#pragma unroll
    for (int n = 0; n < 2; ++n) acc[m][n] = {0.f, 0.f, 0.f, 0.f};

  for (int kk = 0; kk < 4; ++kk) {
    int kbase = kk * 64;
    // stage A: 1024 chunks (128 rows x 8 slots), thread does 2
#pragma unroll
    for (int q = 0; q < 2; ++q)
      gload16(gA + (size_t)q * 64 * 256 + kbase, Albuf + (size_t)(q * 512 + w * 64) * 8);
    // stage B: 512 chunks (64 rows x 8 slots), thread does 1
    gload16(gB + kbase, Blbuf + (size_t)(w * 64) * 8);
    __syncthreads();   // publish staged tile (drains vmcnt); TLP hides latency

#pragma unroll
    for (int ks = 0; ks < 2; ++ks) {
      int sl = (ks * 4 + kb) ^ (fr & 7);
      short8 af[2], bf[2];
#pragma unroll
      for (int m = 0; m < 2; ++m)
        af[m] = *(const short8*)&Albuf[((wr * 32 + m * 16 + fr) * 8 + sl) * 8];
#pragma unroll
      for (int n = 0; n < 2; ++n)
        bf[n] = *(const short8*)&Blbuf[((wc * 32 + n * 16 + fr) * 8 + sl) * 8];
#pragma unroll
      for (int m = 0; m < 2; ++m)
#pragma unroll
        for (int n = 0; n < 2; ++n)
          acc[m][n] = __builtin_amdgcn_mfma_f32_16x16x32_bf16(af[m], bf[n],
                                                              acc[m][n], 0, 0, 0);
    }
    if (kk < 3) __syncthreads();   // protect LDS before next stage overwrites
  }

  // ---- epilogue: positives + exp bucket sums (C/D: row=kb*4+r, col=fr)
  int t = blockIdx.y * 2 + wc;     // this wave's single t (32 cols)
#pragma unroll
  for (int m = 0; m < 2; ++m) {
    int rowg = rowbase + wr * 32 + m * 16 + kb * 4;
#pragma unroll
    for (int r = 0; r < 4; ++r) {
      int u = rowg + r;
      int b = u / 192;
      int urow = u - b * 192;
      int dt = urow - t;
      if (dt >= 0 && dt < 12) {
#pragma unroll
        for (int n = 0; n < 2; ++n) {
          int j = (wc * 32 + n * 16 + fr) & 31;
          if (j == b) pos[u * 12 + dt] = acc[m][n][r];
        }
      }
      float v = expsh(acc[m][0][r]) + expsh(acc[m][1][r]);
      v += __shfl_xor(v, 1); v += __shfl_xor(v, 2);
      v += __shfl_xor(v, 4); v += __shfl_xor(v, 8);
      if (fr == 0) {
        if (t < TAIL0) atomicAdd(&sum0[u], v);
        else tail[(size_t)(t - TAIL0) * NROW + u] = v;
      }
    }
  }
}

// ---- D: per-row loss terms + global reduce + fused final (completion counter)
__global__ void k_loss(const float* __restrict__ sum0, const float* __restrict__ tail,
                       const float* __restrict__ pos, float* acc,
                       unsigned int* cnt, float* __restrict__ out) {
  int u = blockIdx.x * 256 + threadIdx.x;
  int urow = u % 192;
  int smax = urow < 11 ? urow : 11;
  float denom = sum0[u];
  float local = 0.f;
  for (int s = 11; s >= 0; --s) {
    if (s < 11) denom += tail[(size_t)(10 - s) * NROW + u];
    if (s <= smax)
      local += pos[u * 12 + s] - 64.f - __logf(denom) + __logf(32.f * (float)(192 - s));
  }
  float v = local;
  v += __shfl_xor(v, 1);  v += __shfl_xor(v, 2);  v += __shfl_xor(v, 4);
  v += __shfl_xor(v, 8);  v += __shfl_xor(v, 16); v += __shfl_xor(v, 32);
  __shared__ float red[4];
  if ((threadIdx.x & 63) == 0) red[threadIdx.x >> 6] = v;
  __syncthreads();
  if (threadIdx.x == 0) {
    atomicAdd(acc, red[0] + red[1] + red[2] + red[3]);
    __threadfence();
    unsigned int old = atomicAdd(cnt, 1u);
    if (old == 23u) {   // last block: all 24 partials visible
      float tot = atomicAdd(acc, 0.0f);
      out[0] = -tot * (1.0f / NTERMS);
    }
  }
}

extern "C" void kernel_launch(void* const* d_in, const int* in_sizes, int n_in,
                              void* d_out, int out_size, void* d_ws, size_t ws_size,
                              hipStream_t stream) {
  const float* emb = (const float*)d_in[0];
  const float* ctx = (const float*)d_in[1];
  const float* W   = (const float*)d_in[2];
  char* ws = (char*)d_ws;
  ushort* P    = (ushort*)(ws + 0);         // 6144x256 bf16
  ushort* X    = (ushort*)(ws + 3145728);   // 6144x256 bf16
  ushort* Wt   = (ushort*)(ws + 6291456);   // 256x256 bf16
  float*  sum0 = (float*)(ws + 6422528);    // 6144 f32
  float*  acc  = (float*)(ws + 6447104);    // 1 f32   (= sum0+6144)
  unsigned int* cnt = (unsigned int*)(ws + 6447108); // 1 u32 (= sum0+6145)
  float*  tail = (float*)(ws + 6447360);    // 11x6144 f32
  float*  pos  = (float*)(ws + 6717696);    // 6144x12 f32

  k_castW<<<281, 256, 0, stream>>>(W, Wt, sum0);
  k_projX<<<dim3(384, 2), 256, 0, stream>>>(emb, ctx, Wt, X, P);
  k_scores<<<dim3(48, 96), 512, 0, stream>>>(P, X, sum0, tail, pos);
  k_loss<<<24, 256, 0, stream>>>(sum0, tail, pos, acc, cnt, (float*)d_out);
}

// Round 16
// 67.054 us; speedup vs baseline: 1.0688x; 1.0688x over previous
//
#include <hip/hip_runtime.h>
#include <hip/hip_bf16.h>
#include <math.h>

// B=32, T=256, E=C=256, MIN_CONTEXT=64, FUTURE_STEPS=12
// S0=192, NROW=6144, K=256. G = P·X^T (6144x6144), bucketed exp-sums.
// t in [181,192) are singleton tail buckets; bucket0 = t<181. N_terms=71616.

#define NROW 6144
#define TAIL0 181
#define NTERMS 71616.0f
#define LOG2E 1.44269504088896340736f
#define SHIFT2 92.33248261689366f   // 64 * log2(e)

typedef __attribute__((ext_vector_type(8))) short short8;
typedef __attribute__((ext_vector_type(4))) float f32x4;

__device__ __forceinline__ ushort f2bf(float f) {
  union { float f; uint32_t u; } v; v.f = f;
  uint32_t u = v.u;
  return (ushort)((u + 0x7FFFu + ((u >> 16) & 1u)) >> 16);
}
// exp(x - 64) = exp2(x*log2e - 64*log2e)
__device__ __forceinline__ float expsh(float x) {
  return exp2f(fmaf(x, LOG2E, -SHIFT2));
}

// async global->LDS, 16B per lane; lds dst must be wave-uniform base
__device__ __forceinline__ void gload16(const ushort* g, ushort* l) {
  __builtin_amdgcn_global_load_lds((const __attribute__((address_space(1))) void*)g,
                                   (__attribute__((address_space(3))) void*)l, 16, 0, 0);
}

// ---- A0+A1 fused casts + workspace zeroing (blocks >=1792).
__global__ __launch_bounds__(256) void k_cast(const float* __restrict__ ctx,
                                              const float* __restrict__ W,
                                              ushort* __restrict__ X,
                                              ushort* __restrict__ Wt,
                                              float* __restrict__ zbase) {
  int bi = blockIdx.x;
  if (bi < 1536) {
    int idx = bi * 256 + threadIdx.x;   // 393216 float4 chunks
    int row = idx >> 6, f4 = idx & 63;  // row = t*32+j
    int j = row & 31, t = row >> 5;
    float4 f = *(const float4*)(ctx + ((size_t)(j * 256 + 63 + t)) * 256 + f4 * 4);
    ushort4 o;
    o.x = f2bf(f.x); o.y = f2bf(f.y); o.z = f2bf(f.z); o.w = f2bf(f.w);
    ((ushort4*)(X + (size_t)row * 256))[f4] = o;
  } else if (bi < 1792) {
    int c = bi - 1536, e = threadIdx.x;
    Wt[c * 256 + e] = f2bf(W[e * 256 + c]);
  } else {
    int idx = (bi - 1792) * 256 + threadIdx.x;
    if (idx < 6146) zbase[idx] = 0.f;   // sum0[6144] + acc + cnt
  }
}

// ---- A2: P = emb_slice @ W (block = 16-row tile x 128-col half)
__global__ __launch_bounds__(256) void k_proj(const float* __restrict__ emb,
                                              const ushort* __restrict__ Wt,
                                              ushort* __restrict__ P) {
  __shared__ ushort Al[16 * 256];  // 8KB
  int tid = threadIdx.x;
  int rt = blockIdx.x;             // 384 row tiles
  int half = blockIdx.y;           // col half (128 cols)
#pragma unroll
  for (int q = 0; q < 4; ++q) {
    int cc = tid + q * 256;
    int rw = cc >> 6, f4 = cc & 63;
    int u = rt * 16 + rw, b = u / 192, urow = u - b * 192;
    float4 f = *(const float4*)(emb + ((size_t)(b * 256 + 64 + urow)) * 256 + f4 * 4);
    ushort4 o;
    o.x = f2bf(f.x); o.y = f2bf(f.y); o.z = f2bf(f.z); o.w = f2bf(f.w);
    int c8 = f4 >> 1;
    *(ushort4*)&Al[rw * 256 + ((c8 ^ (rw & 7)) * 8) + (f4 & 1) * 4] = o;
  }
  __syncthreads();

  int w = tid >> 6, l = tid & 63;
  int fr = l & 15, kb = l >> 4;
  short8 af[8];
#pragma unroll
  for (int kk = 0; kk < 8; ++kk) {
    int c8 = kk * 4 + kb;
    af[kk] = *(const short8*)&Al[fr * 256 + (c8 ^ (fr & 7)) * 8];
  }
#pragma unroll
  for (int i = 0; i < 2; ++i) {
    int ct = half * 8 + w * 2 + i;
    const short8* bp = (const short8*)(Wt + (size_t)(ct * 16 + fr) * 256);
    f32x4 acc = {0.f, 0.f, 0.f, 0.f};
#pragma unroll
    for (int kk = 0; kk < 8; ++kk)
      acc = __builtin_amdgcn_mfma_f32_16x16x32_bf16(af[kk], bp[kk * 4 + kb], acc, 0, 0, 0);
#pragma unroll
    for (int r = 0; r < 4; ++r)
      P[(size_t)(rt * 16 + kb * 4 + r) * 256 + ct * 16 + fr] = f2bf(acc[r]);
  }
}

// ---- B: G = P·X^T — r12 wave economics (wave 32x32, acc[2][2] = 16 AGPR,
// ~40 unified regs -> 8 waves/SIMD) scaled to block 128x128 with 1024 threads /
// 16 waves (4 wr x 4 wc): halves A-staging traffic (A staged once covers 2x
// the output) and halves blocks + barrier events. BK=64, 4 rounds of
// stage -> barrier -> ds_read+MFMA -> barrier, single-buffered 32KB LDS,
// 2 blocks/CU = 100% wave cap. By-major grid: concurrent blocks share `by`
// -> disjoint atomic targets (r10 lesson).
// LDS rows hold 8 x 16B chunks, slot XOR-swizzled (slot ^ (row&7)) via
// pre-swizzled GLOBAL source addresses -> conflict-free ds_read_b128.
__global__ __launch_bounds__(1024, 8) void k_scores(const ushort* __restrict__ P,
                                                    const ushort* __restrict__ X,
                                                    float* __restrict__ sum0,
                                                    float* __restrict__ tail,
                                                    float* __restrict__ pos) {
  __shared__ ushort Albuf[128 * 64];   // 16KB
  __shared__ ushort Blbuf[128 * 64];   // 16KB
  int tid = threadIdx.x;               // 0..1023
  int w = tid >> 6, l = tid & 63;      // w 0..15
  int wr = w >> 2, wc = w & 3;         // wr 0..3, wc 0..3
  int rowbase = blockIdx.x * 128;
  int colbase = blockIdx.y * 128;

  int fr = l & 15, kb = l >> 4;

  // staging geometry: A chunk ci = tid, B chunk ci = tid (1024 chunks each).
  // row = ci>>3 (0..127), slot = ci&7 ; src k-chunk = slot ^ (row&7)
  int r0 = tid >> 3;
  int srcc = (tid & 7) ^ (r0 & 7);
  const ushort* gA = P + (size_t)(rowbase + r0) * 256 + srcc * 8;
  const ushort* gB = X + (size_t)(colbase + r0) * 256 + srcc * 8;

  f32x4 acc[2][2];
#pragma unroll
  for (int m = 0; m < 2; ++m)
#pragma unroll
    for (int n = 0; n < 2; ++n) acc[m][n] = {0.f, 0.f, 0.f, 0.f};

  for (int kk = 0; kk < 4; ++kk) {
    int kbase = kk * 64;
    gload16(gA + kbase, Albuf + (size_t)(w * 64) * 8);   // 1 chunk/thread
    gload16(gB + kbase, Blbuf + (size_t)(w * 64) * 8);   // 1 chunk/thread
    __syncthreads();   // publish staged tile (drains vmcnt); TLP hides latency

#pragma unroll
    for (int ks = 0; ks < 2; ++ks) {
      int sl = (ks * 4 + kb) ^ (fr & 7);
      short8 af[2], bf[2];
#pragma unroll
      for (int m = 0; m < 2; ++m)
        af[m] = *(const short8*)&Albuf[((wr * 32 + m * 16 + fr) * 8 + sl) * 8];
#pragma unroll
      for (int n = 0; n < 2; ++n)
        bf[n] = *(const short8*)&Blbuf[((wc * 32 + n * 16 + fr) * 8 + sl) * 8];
#pragma unroll
      for (int m = 0; m < 2; ++m)
#pragma unroll
        for (int n = 0; n < 2; ++n)
          acc[m][n] = __builtin_amdgcn_mfma_f32_16x16x32_bf16(af[m], bf[n],
                                                              acc[m][n], 0, 0, 0);
    }
    if (kk < 3) __syncthreads();   // protect LDS before next stage overwrites
  }

  // ---- epilogue: positives + exp bucket sums (C/D: row=kb*4+r, col=fr)
  int t = blockIdx.y * 4 + wc;     // this wave's single t (32 cols)
#pragma unroll
  for (int m = 0; m < 2; ++m) {
    int rowg = rowbase + wr * 32 + m * 16 + kb * 4;
#pragma unroll
    for (int r = 0; r < 4; ++r) {
      int u = rowg + r;
      int b = u / 192;
      int urow = u - b * 192;
      int dt = urow - t;
      if (dt >= 0 && dt < 12) {
#pragma unroll
        for (int n = 0; n < 2; ++n) {
          int j = (wc * 32 + n * 16 + fr) & 31;
          if (j == b) pos[u * 12 + dt] = acc[m][n][r];
        }
      }
      float v = expsh(acc[m][0][r]) + expsh(acc[m][1][r]);
      v += __shfl_xor(v, 1); v += __shfl_xor(v, 2);
      v += __shfl_xor(v, 4); v += __shfl_xor(v, 8);
      if (fr == 0) {
        if (t < TAIL0) atomicAdd(&sum0[u], v);
        else tail[(size_t)(t - TAIL0) * NROW + u] = v;
      }
    }
  }
}

// ---- D: per-row loss terms + global reduce + fused final (completion counter)
__global__ void k_loss(const float* __restrict__ sum0, const float* __restrict__ tail,
                       const float* __restrict__ pos, float* acc,
                       unsigned int* cnt, float* __restrict__ out) {
  int u = blockIdx.x * 256 + threadIdx.x;
  int urow = u % 192;
  int smax = urow < 11 ? urow : 11;
  float denom = sum0[u];
  float local = 0.f;
  for (int s = 11; s >= 0; --s) {
    if (s < 11) denom += tail[(size_t)(10 - s) * NROW + u];
    if (s <= smax)
      local += pos[u * 12 + s] - 64.f - __logf(denom) + __logf(32.f * (float)(192 - s));
  }
  float v = local;
  v += __shfl_xor(v, 1);  v += __shfl_xor(v, 2);  v += __shfl_xor(v, 4);
  v += __shfl_xor(v, 8);  v += __shfl_xor(v, 16); v += __shfl_xor(v, 32);
  __shared__ float red[4];
  if ((threadIdx.x & 63) == 0) red[threadIdx.x >> 6] = v;
  __syncthreads();
  if (threadIdx.x == 0) {
    atomicAdd(acc, red[0] + red[1] + red[2] + red[3]);
    __threadfence();
    unsigned int old = atomicAdd(cnt, 1u);
    if (old == 23u) {   // last block: all 24 partials visible
      float tot = atomicAdd(acc, 0.0f);
      out[0] = -tot * (1.0f / NTERMS);
    }
  }
}

extern "C" void kernel_launch(void* const* d_in, const int* in_sizes, int n_in,
                              void* d_out, int out_size, void* d_ws, size_t ws_size,
                              hipStream_t stream) {
  const float* emb = (const float*)d_in[0];
  const float* ctx = (const float*)d_in[1];
  const float* W   = (const float*)d_in[2];
  char* ws = (char*)d_ws;
  ushort* P    = (ushort*)(ws + 0);         // 6144x256 bf16
  ushort* X    = (ushort*)(ws + 3145728);   // 6144x256 bf16
  ushort* Wt   = (ushort*)(ws + 6291456);   // 256x256 bf16
  float*  sum0 = (float*)(ws + 6422528);    // 6144 f32
  float*  acc  = (float*)(ws + 6447104);    // 1 f32   (= sum0+6144)
  unsigned int* cnt = (unsigned int*)(ws + 6447108); // 1 u32 (= sum0+6145)
  float*  tail = (float*)(ws + 6447360);    // 11x6144 f32
  float*  pos  = (float*)(ws + 6717696);    // 6144x12 f32

  k_cast<<<1817, 256, 0, stream>>>(ctx, W, X, Wt, sum0);
  k_proj<<<dim3(384, 2), 256, 0, stream>>>(emb, Wt, P);
  k_scores<<<dim3(48, 48), 1024, 0, stream>>>(P, X, sum0, tail, pos);
  k_loss<<<24, 256, 0, stream>>>(sum0, tail, pos, acc, cnt, (float*)d_out);
}